// Round 5
// baseline (108.576 us; speedup 1.0000x reference)
//
#include <hip/hip_runtime.h>

// Problem constants
#define BB 8
#define HH 640
#define WW 640
#define HWN (HH * WW)          // 409600 pixels per batch
#define NUM_INST 16
#define NBLK 128               // blocks per batch -> 1024 total = 4 blocks/CU (proven)
#define NBLK_TOT (NBLK * BB)   // 1024
#define THREADS 256
#define NV 36                  // 16 s12 | 16 cnt | pos, all, or, posCnt
#define NVEC (HWN / 4)         // 102400 float4 per batch
#define VPB (NVEC / NBLK)      // 800 float4 per block: 3 full rounds + 32-thread tail
#define TAIL (VPB - 3 * THREADS)   // 32

// ws layout: ws[v * NBLK_TOT + g], g = b*NBLK + blockIdx.x. 36*1024*4 = 147456 B.
// Plain stores, no zero-init needed.

__device__ __forceinline__ void process_pixel(
    float p1, float p2, float c, float t, int k,
    float* s12, unsigned* cnt_s,
    float& lgPos, float& lgAll, float& lgOr, float& accCnt)
{
    float andp = p1 * p2;
    bool tpos = (t != 0.0f);
    bool cpos = (c != 0.0f);
    // BCE(and_preds, overlap): overlap exactly 0/1 -> one log, select the argument.
    // Clip at -100 never engages: inputs in [1e-4, 1-1e-4].
    // Accumulate log2; scale by ln2 and negate ONCE in the epilogue (absmax=0 since R2).
    float argA = tpos ? andp : (1.0f - andp);
    float lg = __log2f(argA);          // raw v_log_f32
    lgAll += lg;
    lgPos = fmaf(c, lg, lgPos);        // c is exactly 0.0/1.0
    accCnt += c;
    // BCE(max(p1,p2), conf): conf exactly 0/1
    float mx = fmaxf(p1, p2);
    float argO = cpos ? mx : (1.0f - mx);
    lgOr += __log2f(argO);
    // instance term: |d1-d2| = |s1-s2|/cnt, accumulate e1-e2 only
    float ao = t * andp;               // t is exactly 0.0/1.0
    float d1 = fmaxf(p1, ao) - 1.0f;
    float d2 = fmaxf(p2, ao) - 1.0f;
    float e12 = (d1 - d2) * (d1 + d2);
    // Register binning ladder (~0.7 us per block chip-resident). R1 proved LDS
    // float atomics lower to a CAS loop (+23 us). Counts ride the scalar pipe.
    #pragma unroll
    for (int j = 0; j < NUM_INST; ++j) {
        bool m = (k == j);
        s12[j] += m ? e12 : 0.0f;                       // v_cmp + cndmask + add
        cnt_s[j] += (unsigned)__popcll(__ballot(m));    // s_bcnt1 + s_add (scalar pipe)
    }
}

// (256,4): min 4 waves/EU -> VGPR cap 128; ~90 live regs at peak here (4-round
// payload is statically indexed -> registers, rule #20). 4 blocks/CU exact.
__global__ __launch_bounds__(THREADS, 4) void overlap_main_kernel(
    const float* __restrict__ preds, const float* __restrict__ conf,
    const int* __restrict__ inst, const float* __restrict__ overlap,
    float* __restrict__ ws)
{
    const int b   = blockIdx.y;
    const int tid = threadIdx.x;
    const int bs  = blockIdx.x * VPB;   // contiguous 800-vec4 chunk per block

    const float4* p1v = (const float4*)(preds + (size_t)b * 2 * HWN);
    const float4* p2v = p1v + NVEC;
    const float4* cv  = (const float4*)(conf    + (size_t)b * HWN);
    const float4* tv  = (const float4*)(overlap + (size_t)b * HWN);
    const int4*   kv  = (const int4*)(inst      + (size_t)b * HWN);

    float s12[NUM_INST];
    unsigned cnt_s[NUM_INST];
    #pragma unroll
    for (int j = 0; j < NUM_INST; ++j) { s12[j] = 0.0f; cnt_s[j] = 0u; }
    float lgPos = 0.0f, lgAll = 0.0f, lgOr = 0.0f, accCnt = 0.0f;

    // Software pipeline: issue all 3 full rounds' loads (15 independent
    // dwordx4, ~60 payload VGPRs) BEFORE any compute; the tail load is issued
    // after round-0 compute. Each wave then has >=2 rounds of compute in
    // flight against every load's latency -> duty cycle ~1 (R4 ran ~55% of
    // achievable BW; the serial {load, drain, compute} round was the gap).
    float4 A[4], Bv[4], C[4], T[4];
    int4   K[4];
    #pragma unroll
    for (int r = 0; r < 3; ++r) {
        int i = bs + r * THREADS + tid;
        A[r]  = p1v[i];
        Bv[r] = p2v[i];
        C[r]  = cv[i];
        T[r]  = tv[i];
        K[r]  = kv[i];
    }
    const bool tl = tid < TAIL;   // 32-lane remainder (ballot counts active lanes)

    // compute round 0 (compiler waits vmcnt for round-0 regs only; rounds 1,2 stay in flight)
    process_pixel(A[0].x, Bv[0].x, C[0].x, T[0].x, K[0].x, s12, cnt_s, lgPos, lgAll, lgOr, accCnt);
    process_pixel(A[0].y, Bv[0].y, C[0].y, T[0].y, K[0].y, s12, cnt_s, lgPos, lgAll, lgOr, accCnt);
    process_pixel(A[0].z, Bv[0].z, C[0].z, T[0].z, K[0].z, s12, cnt_s, lgPos, lgAll, lgOr, accCnt);
    process_pixel(A[0].w, Bv[0].w, C[0].w, T[0].w, K[0].w, s12, cnt_s, lgPos, lgAll, lgOr, accCnt);

    if (tl) {
        int i = bs + 3 * THREADS + tid;
        A[3]  = p1v[i];
        Bv[3] = p2v[i];
        C[3]  = cv[i];
        T[3]  = tv[i];
        K[3]  = kv[i];
    }

    #pragma unroll
    for (int r = 1; r < 3; ++r) {
        process_pixel(A[r].x, Bv[r].x, C[r].x, T[r].x, K[r].x, s12, cnt_s, lgPos, lgAll, lgOr, accCnt);
        process_pixel(A[r].y, Bv[r].y, C[r].y, T[r].y, K[r].y, s12, cnt_s, lgPos, lgAll, lgOr, accCnt);
        process_pixel(A[r].z, Bv[r].z, C[r].z, T[r].z, K[r].z, s12, cnt_s, lgPos, lgAll, lgOr, accCnt);
        process_pixel(A[r].w, Bv[r].w, C[r].w, T[r].w, K[r].w, s12, cnt_s, lgPos, lgAll, lgOr, accCnt);
    }
    if (tl) {
        process_pixel(A[3].x, Bv[3].x, C[3].x, T[3].x, K[3].x, s12, cnt_s, lgPos, lgAll, lgOr, accCnt);
        process_pixel(A[3].y, Bv[3].y, C[3].y, T[3].y, K[3].y, s12, cnt_s, lgPos, lgAll, lgOr, accCnt);
        process_pixel(A[3].z, Bv[3].z, C[3].z, T[3].z, K[3].z, s12, cnt_s, lgPos, lgAll, lgOr, accCnt);
        process_pixel(A[3].w, Bv[3].w, C[3].w, T[3].w, K[3].w, s12, cnt_s, lgPos, lgAll, lgOr, accCnt);
    }

    // Butterfly-reduce the 20 per-lane floats (cnt bins are wave-uniform SGPRs)
    float fv[20];
    #pragma unroll
    for (int j = 0; j < NUM_INST; ++j) fv[j] = s12[j];
    fv[16] = lgPos; fv[17] = lgAll; fv[18] = lgOr; fv[19] = accCnt;
    #pragma unroll
    for (int s = 32; s > 0; s >>= 1) {
        #pragma unroll
        for (int v = 0; v < 20; ++v) fv[v] += __shfl_xor(fv[v], s, 64);
    }

    __shared__ float wsum[4][NV];
    const int wave = tid >> 6;
    const int lane = tid & 63;
    if (lane == 0) {
        #pragma unroll
        for (int j = 0; j < NUM_INST; ++j) {
            wsum[wave][j]      = fv[j];
            wsum[wave][16 + j] = (float)cnt_s[j];
        }
        wsum[wave][32] = fv[16];   // sum(c*log2)
        wsum[wave][33] = fv[17];   // sum(log2) and-term
        wsum[wave][34] = fv[18];   // sum(log2) or-term
        wsum[wave][35] = fv[19];   // posCnt
    }
    __syncthreads();
    if (tid < NV) {
        float s = wsum[0][tid] + wsum[1][tid] + wsum[2][tid] + wsum[3][tid];
        if (tid >= 32 && tid < 35)
            s = -0.69314718055994530942f * s;   // log2 -> -ln: posSum, allSum, orSum
        int g = blockIdx.y * NBLK + blockIdx.x;
        ws[tid * NBLK_TOT + g] = s;             // plain store, no atomics
    }
}

__global__ __launch_bounds__(320) void overlap_finalize_kernel(
    const float* __restrict__ ws, float* __restrict__ out)
{
    __shared__ float seg[BB][NV];
    __shared__ float perkey[BB][NUM_INST];
    __shared__ float pres[BB][NUM_INST];
    __shared__ float binst[BB];
    const int t = threadIdx.x;   // 320 >= 8*36 = 288

    if (t < BB * NV) {
        int b = t / NV, v = t - (t / NV) * NV;
        const float4* p = (const float4*)(ws + v * NBLK_TOT + b * NBLK);
        float4 s4 = {0.0f, 0.0f, 0.0f, 0.0f};
        #pragma unroll 8
        for (int i = 0; i < NBLK / 4; ++i) {   // 32 independent float4 loads
            float4 q = p[i];
            s4.x += q.x; s4.y += q.y; s4.z += q.z; s4.w += q.w;
        }
        seg[b][v] = (s4.x + s4.y) + (s4.z + s4.w);
    }
    __syncthreads();

    if (t < BB * NUM_INST) {
        int b = t >> 4, k = t & 15;
        float c = seg[b][16 + k];
        bool present = c > 0.0f;
        float sc = present ? c : 1.0f;
        perkey[b][k] = present ? (1.0f - fabsf(seg[b][k]) / sc) : 0.0f;
        pres[b][k]   = present ? 1.0f : 0.0f;
    }
    __syncthreads();

    if (t < BB) {
        float s = 0.0f, nk = 0.0f;
        for (int k = 0; k < NUM_INST; ++k) { s += perkey[t][k]; nk += pres[t][k]; }
        binst[t] = s / nk;
    }
    __syncthreads();

    if (t == 0) {
        float instLoss = 0.0f, posS = 0.0f, allS = 0.0f, orS = 0.0f, posC = 0.0f;
        for (int b = 0; b < BB; ++b) {
            instLoss += binst[b];
            posS += seg[b][32];
            allS += seg[b][33];
            orS  += seg[b][34];
            posC += seg[b][35];
        }
        instLoss *= (1.0f / (float)BB);
        const float N = (float)BB * (float)HWN;
        float negS = allS - posS;
        float andLoss = posS / posC + negS / (N - posC);
        float orLoss  = orS / N;
        out[0] = 0.5f * andLoss + 0.25f * orLoss + 0.25f * instLoss;
    }
}

extern "C" void kernel_launch(void* const* d_in, const int* in_sizes, int n_in,
                              void* d_out, int out_size, void* d_ws, size_t ws_size,
                              hipStream_t stream) {
    const float* preds   = (const float*)d_in[0];
    const float* conf    = (const float*)d_in[1];
    const int*   inst    = (const int*)d_in[2];
    const float* overlap = (const float*)d_in[3];
    // d_in[4] (inds) is unused by the reference computation.
    float* ws  = (float*)d_ws;
    float* out = (float*)d_out;

    dim3 grid(NBLK, BB);
    overlap_main_kernel<<<grid, THREADS, 0, stream>>>(preds, conf, inst, overlap, ws);
    overlap_finalize_kernel<<<1, 320, 0, stream>>>(ws, out);
}